// Round 1
// baseline (1930.972 us; speedup 1.0000x reference)
//
#include <hip/hip_runtime.h>

// Problem constants
#define GM   1024
#define GK   4096
#define GN   50257
#define NPAD 50304          // 393 * 128

typedef __attribute__((ext_vector_type(8))) __bf16 bf16x8;
typedef __attribute__((ext_vector_type(4))) float  f32x4;

// ---- fp32 -> bf16 (round to nearest even) ----
__device__ __forceinline__ short f2bf(float f) {
    unsigned int u = __float_as_uint(f);
    u += 0x7fffu + ((u >> 16) & 1u);
    return (short)(u >> 16);
}

// ---- async global->LDS, 16B per lane ----
__device__ __forceinline__ void gload_lds16(const void* g, void* l) {
    __builtin_amdgcn_global_load_lds(
        (const __attribute__((address_space(1))) void*)g,
        (__attribute__((address_space(3))) void*)l,
        16, 0, 0);
}

// ---- x fp32 [1024][4096] -> bf16, one float4 chunk per thread ----
__global__ __launch_bounds__(256) void cvt_x(const float* __restrict__ s,
                                             short* __restrict__ d) {
    int i = blockIdx.x * 256 + threadIdx.x;           // 1,048,576 chunks exact
    float4 v = ((const float4*)s)[i];
    short4 o;
    o.x = f2bf(v.x); o.y = f2bf(v.y); o.z = f2bf(v.z); o.w = f2bf(v.w);
    ((short4*)d)[i] = o;
}

// ---- W fp32 [50257][4096] -> bf16 [50304][4096], pad rows zeroed ----
__global__ __launch_bounds__(256) void cvt_w(const float* __restrict__ s,
                                             short* __restrict__ d) {
    int i = blockIdx.x * 256 + threadIdx.x;           // 51,511,296 chunks exact
    int row = i >> 10;                                 // 1024 chunks per row
    short4 o;
    if (row < GN) {
        float4 v = ((const float4*)s)[i];
        o.x = f2bf(v.x); o.y = f2bf(v.y); o.z = f2bf(v.z); o.w = f2bf(v.w);
    } else {
        o.x = 0; o.y = 0; o.z = 0; o.w = 0;
    }
    ((short4*)d)[i] = o;
}

// ---- C[1024][50257] = A[1024][4096] * B[50304][4096]^T + bias ----
// m97 structure: 128x128 tile, BK=32, 4 waves (2x2), each wave 4x4 MFMA 16x16x32.
__global__ __launch_bounds__(256, 2) void gemm_bt(const __bf16* __restrict__ A,
                                                  const __bf16* __restrict__ B,
                                                  const float* __restrict__ bias,
                                                  float* __restrict__ C) {
    __shared__ __bf16 lA[128 * 32];
    __shared__ __bf16 lB[128 * 32];

    const int tid  = threadIdx.x;
    const int wave = tid >> 6;
    const int lane = tid & 63;
    // m-tile fast so the 8 M-tiles of one N-tile are dispatch-adjacent
    const int m0 = (blockIdx.x & 7) << 7;
    const int n0 = (blockIdx.x >> 3) << 7;

    // staging addresses: LDS byte offset o covers tile row o/64, col-byte o%64
    const int o0 = wave * 1024 + lane * 16;
    const int r0 = o0 >> 6;
    const int c0 = o0 & 63;
    const size_t rb = (size_t)GK * 2;                 // 8192 B per row
    const char* pA0 = (const char*)A + (size_t)(m0 + r0) * rb + c0;
    const char* pA1 = pA0 + 64 * rb;
    const char* pB0 = (const char*)B + (size_t)(n0 + r0) * rb + c0;
    const char* pB1 = pB0 + 64 * rb;
    __bf16* lA0 = &lA[(size_t)wave * 512];
    __bf16* lA1 = &lA[(size_t)(wave + 4) * 512];
    __bf16* lB0 = &lB[(size_t)wave * 512];
    __bf16* lB1 = &lB[(size_t)(wave + 4) * 512];

    f32x4 acc[4][4] = {};

    const int wm   = (wave & 1) * 64;
    const int wn   = (wave >> 1) * 64;
    const int frow = lane & 15;
    const int fk   = (lane >> 4) * 8;
    const int aoff = (wm + frow) * 32 + fk;
    const int boff = (wn + frow) * 32 + fk;

    for (int kt = 0; kt < GK / 32; ++kt) {
        __syncthreads();                               // prev tile consumed
        gload_lds16(pA0, lA0);
        gload_lds16(pA1, lA1);
        gload_lds16(pB0, lB0);
        gload_lds16(pB1, lB1);
        pA0 += 64; pA1 += 64; pB0 += 64; pB1 += 64;
        __syncthreads();                               // staging complete (vmcnt drain)

        bf16x8 aF[4], bF[4];
#pragma unroll
        for (int i = 0; i < 4; ++i)
            aF[i] = *(const bf16x8*)&lA[aoff + i * 16 * 32];
#pragma unroll
        for (int j = 0; j < 4; ++j)
            bF[j] = *(const bf16x8*)&lB[boff + j * 16 * 32];
#pragma unroll
        for (int i = 0; i < 4; ++i)
#pragma unroll
            for (int j = 0; j < 4; ++j)
                acc[i][j] = __builtin_amdgcn_mfma_f32_16x16x32_bf16(
                    aF[i], bF[j], acc[i][j], 0, 0, 0);
    }

    // epilogue: D elem (reg r, lane l) -> row = (l>>4)*4 + r, col = l&15
    const int crow = (lane >> 4) * 4;
    const int ccol = lane & 15;
#pragma unroll
    for (int j = 0; j < 4; ++j) {
        const int col = n0 + wn + j * 16 + ccol;
        if (col < GN) {
            const float bj = bias[col];
#pragma unroll
            for (int i = 0; i < 4; ++i) {
                const int row = m0 + wm + i * 16 + crow;
                float* cp = C + (size_t)row * GN + col;
#pragma unroll
                for (int r = 0; r < 4; ++r)
                    cp[(size_t)r * GN] = acc[i][j][r] + bj;
            }
        }
    }
}

// ---- in-place row softmax over [1024][50257] ----
__global__ __launch_bounds__(256) void softmax_rows(float* __restrict__ C) {
    float* row = C + (size_t)blockIdx.x * GN;
    const int tid = threadIdx.x;
    __shared__ float red[4];

    // pass 1: max
    float m = -1e30f;
    for (int i = tid; i < GN; i += 256) m = fmaxf(m, row[i]);
#pragma unroll
    for (int o = 32; o > 0; o >>= 1) m = fmaxf(m, __shfl_xor(m, o, 64));
    if ((tid & 63) == 0) red[tid >> 6] = m;
    __syncthreads();
    m = fmaxf(fmaxf(red[0], red[1]), fmaxf(red[2], red[3]));
    __syncthreads();

    // pass 2: sum of exp
    float s = 0.f;
    for (int i = tid; i < GN; i += 256) s += __expf(row[i] - m);
#pragma unroll
    for (int o = 32; o > 0; o >>= 1) s += __shfl_xor(s, o, 64);
    if ((tid & 63) == 0) red[tid >> 6] = s;
    __syncthreads();
    s = red[0] + red[1] + red[2] + red[3];
    const float inv = 1.0f / s;

    // pass 3: normalize
    for (int i = tid; i < GN; i += 256) row[i] = __expf(row[i] - m) * inv;
}

extern "C" void kernel_launch(void* const* d_in, const int* in_sizes, int n_in,
                              void* d_out, int out_size, void* d_ws, size_t ws_size,
                              hipStream_t stream) {
    const float* x = (const float*)d_in[0];   // [1024][4096]
    const float* W = (const float*)d_in[1];   // [50257][4096]
    const float* b = (const float*)d_in[2];   // [50257]
    float* out = (float*)d_out;               // [1024][50257]

    // ws layout: x_bf16 (8,388,608 B) | W_bf16 padded (412,090,368 B)
    short* xb = (short*)d_ws;
    short* Wb = (short*)((char*)d_ws + (size_t)GM * GK * 2);

    cvt_x<<<4096, 256, 0, stream>>>(x, xb);                       // 1M chunks
    cvt_w<<<201216, 256, 0, stream>>>(W, Wb);                     // 51.5M chunks
    gemm_bt<<<(NPAD / 128) * (GM / 128), 256, 0, stream>>>(
        (const __bf16*)xb, (const __bf16*)Wb, b, out);            // 3144 blocks
    softmax_rows<<<GM, 256, 0, stream>>>(out);
}